// Round 1
// baseline (1045.666 us; speedup 1.0000x reference)
//
#include <hip/hip_runtime.h>
#include <math.h>

#define PI_F 3.14159265358979323846f

__device__ inline float2 cmulf(float2 a, float2 b) {
    return make_float2(a.x * b.x - a.y * b.y, a.x * b.y + a.y * b.x);
}

// 512-point Stockham radix-2 FFT over NCOLS interleaved transforms.
// Data in a[col*512 + i]; b is ping-pong workspace. 256 threads.
// tbl[k] = exp(-2*pi*i*k/512), k in [0,256). inv: conjugate twiddles (no 1/N).
// Returns pointer to buffer holding the (natural-order) result.
template <int NCOLS>
__device__ inline float2* fft512(float2* a, float2* b, const float2* tbl, int tid, bool inv) {
    for (int st = 0; st < 9; ++st) {
        int p = tid >> st;
        float2 w = tbl[p << st];
        if (inv) w.y = -w.y;
        int i0 = tid;
        int i1 = tid + 256;
        int o0 = tid + ((tid >> st) << st);  // q + 2*s*p  (q + s*p == tid)
        int o1 = o0 + (1 << st);
#pragma unroll
        for (int k = 0; k < NCOLS; ++k) {
            float2 A = a[k * 512 + i0];
            float2 B = a[k * 512 + i1];
            float2 s = make_float2(A.x + B.x, A.y + B.y);
            float2 d = make_float2(A.x - B.x, A.y - B.y);
            b[k * 512 + o0] = s;
            b[k * 512 + o1] = cmulf(d, w);
        }
        __syncthreads();
        float2* t = a; a = b; b = t;
    }
    return a;
}

__device__ inline void build_tbl(float2* tbl, int tid) {
    float ang = -2.0f * PI_F * (float)tid * (1.0f / 512.0f);
    tbl[tid] = make_float2(cosf(ang), sinf(ang));
}

// K1: real FFT of each row of x (as complex with imag 0).
// x: [128][512][512] float.  G: [128][512][257] float2 (natural layout).
__global__ __launch_bounds__(256) void k_row_rfft(const float* __restrict__ x,
                                                  float2* __restrict__ G) {
    __shared__ float2 b0[512], b1[512], tbl[256];
    int tid = threadIdx.x;
    int row = blockIdx.x;  // nc*512 + h
    build_tbl(tbl, tid);
    const float* xr = x + (size_t)row * 512;
    b0[tid]       = make_float2(xr[tid], 0.0f);
    b0[tid + 256] = make_float2(xr[tid + 256], 0.0f);
    __syncthreads();
    float2* res = fft512<1>(b0, b1, tbl, tid, false);
    float2* g = G + (size_t)row * 257;
    g[tid] = res[tid];
    if (tid == 0) g[256] = res[256];
}

// K2: FFT along h for 4 adjacent columns v0..v0+3.
// G: [128][512][257] float2 -> XT: [128][257][512] float2 (v-major).
__global__ __launch_bounds__(256) void k_col_fft(const float2* __restrict__ G,
                                                 float2* __restrict__ XT) {
    __shared__ float2 b0[2048], b1[2048], tbl[256];
    int tid = threadIdx.x;
    int nc = blockIdx.x / 65;
    int v0 = (blockIdx.x % 65) * 4;
    build_tbl(tbl, tid);
#pragma unroll
    for (int i = 0; i < 8; ++i) {
        int e = tid + 256 * i;          // 2048 elements: (h, k)
        int k = e & 3, h = e >> 2;
        int v = v0 + k;
        float2 val = make_float2(0.0f, 0.0f);
        if (v < 257) val = G[((size_t)nc * 512 + h) * 257 + v];
        b0[k * 512 + h] = val;
    }
    __syncthreads();
    float2* res = fft512<4>(b0, b1, tbl, tid, false);
#pragma unroll
    for (int k = 0; k < 4; ++k) {
        int v = v0 + k;
        if (v < 257) {
            float2* dst = XT + ((size_t)nc * 257 + v) * 512;
            dst[tid]       = res[k * 512 + tid];
            dst[tid + 256] = res[k * 512 + tid + 256];
        }
    }
}

// K3: complex 3x3 conv, 16->16 channels, zero padding, on the half-spectrum.
// Y[n,o,u,v] = b[o] + sum_{c,i,j} w[c,o,1+i,1+j] * X[n,c,u-i,v-j]
// XT layout [n][c][v][u]; YT layout [n][o][v][u].
// Block: one (n, v, 64-wide u tile); threads = 16 o x 16 u lanes, 4 u per thread.
__global__ __launch_bounds__(256) void k_conv(const float2* __restrict__ XT,
                                              float2* __restrict__ YT,
                                              const float* __restrict__ wr,
                                              const float* __restrict__ wi,
                                              const float* __restrict__ br,
                                              const float* __restrict__ bi) {
    __shared__ float2 Xs[16 * 3 * 66];  // [c][dv][uu]
    __shared__ float2 Ws[16 * 9 * 16];  // [c][tap][o] = (wr, wi)
    int tid = threadIdx.x;
    int bid = blockIdx.x;
    int ut = bid & 7;
    int rest = bid >> 3;
    int v = rest % 257;
    int n = rest / 257;
    int u0 = ut * 64;
    // weights: original linear l -> c = l/144, o = (l/9)%16, t = l%9
#pragma unroll
    for (int kk = 0; kk < 9; ++kk) {
        int l = tid + 256 * kk;  // covers [0,2304)
        int c = l / 144, o = (l / 9) % 16, t = l % 9;
        Ws[(c * 9 + t) * 16 + o] = make_float2(wr[l], wi[l]);
    }
    // X tile with halo, zero-padded: 16*3*66 = 3168
    for (int l = tid; l < 3168; l += 256) {
        int c = l / 198;
        int rem = l % 198;
        int dv = rem / 66;
        int uu = rem % 66;
        int vg = v - 1 + dv;
        int ug = u0 - 1 + uu;
        float2 val = make_float2(0.0f, 0.0f);
        if (vg >= 0 && vg < 257 && ug >= 0 && ug < 512)
            val = XT[(((size_t)n * 16 + c) * 257 + vg) * 512 + ug];
        Xs[l] = val;
    }
    __syncthreads();
    int o = tid >> 4, ul = tid & 15;
    float2 acc[4];
    float brv = br[o], biv = bi[o];
#pragma unroll
    for (int r = 0; r < 4; ++r) acc[r] = make_float2(brv, biv);
    for (int c = 0; c < 16; ++c) {
#pragma unroll
        for (int t = 0; t < 9; ++t) {
            int ki = t / 3, kj = t % 3;
            float2 wv = Ws[(c * 9 + t) * 16 + o];
            const float2* xp = &Xs[(c * 3 + (2 - kj)) * 66 + (2 - ki) + ul];
#pragma unroll
            for (int r = 0; r < 4; ++r) {
                float2 X = xp[r * 16];
                acc[r].x += wv.x * X.x - wv.y * X.y;
                acc[r].y += wv.x * X.y + wv.y * X.x;
            }
        }
    }
    float2* yp = YT + (((size_t)n * 16 + o) * 257 + v) * 512 + u0;
#pragma unroll
    for (int r = 0; r < 4; ++r) yp[ul + r * 16] = acc[r];
}

// K4: inverse FFT along u (scale 1/512) for 4 columns.
// YT: [128][257][512] -> ZT: [128][257][512] (v-major, index h).
__global__ __launch_bounds__(256) void k_col_ifft(const float2* __restrict__ YT,
                                                  float2* __restrict__ ZT) {
    __shared__ float2 b0[2048], b1[2048], tbl[256];
    int tid = threadIdx.x;
    int no = blockIdx.x / 65;
    int v0 = (blockIdx.x % 65) * 4;
    build_tbl(tbl, tid);
#pragma unroll
    for (int k = 0; k < 4; ++k) {
        int v = v0 + k;
        const float2* src = YT + ((size_t)no * 257 + (v < 257 ? v : 256)) * 512;
        b0[k * 512 + tid]       = src[tid];
        b0[k * 512 + tid + 256] = src[tid + 256];
    }
    __syncthreads();
    float2* res = fft512<4>(b0, b1, tbl, tid, true);
    const float sc = 1.0f / 512.0f;
#pragma unroll
    for (int k = 0; k < 4; ++k) {
        int v = v0 + k;
        if (v < 257) {
            float2* dst = ZT + ((size_t)no * 257 + v) * 512;
            float2 r0 = res[k * 512 + tid];
            float2 r1 = res[k * 512 + tid + 256];
            dst[tid]       = make_float2(r0.x * sc, r0.y * sc);
            dst[tid + 256] = make_float2(r1.x * sc, r1.y * sc);
        }
    }
}

// K5: irfft along v for 4 rows h0..h0+3.
// ZT: [128][257][512] (v-major, index h) -> out: [128][512][512] float.
// pocketfft c2r semantics: imag of DC and Nyquist bins ignored.
__global__ __launch_bounds__(256) void k_row_irfft(const float2* __restrict__ ZT,
                                                   float* __restrict__ out) {
    __shared__ float2 b0[2048], b1[2048], tbl[256];
    int tid = threadIdx.x;
    int no = blockIdx.x / 128;
    int h0 = (blockIdx.x % 128) * 4;
    build_tbl(tbl, tid);
    // load v in [0,257) for 4 rows: 1028 elements
#pragma unroll
    for (int i = 0; i < 5; ++i) {
        int e = tid + 256 * i;
        if (e < 1028) {
            int k = e & 3, vv = e >> 2;
            float2 val = ZT[((size_t)no * 257 + vv) * 512 + h0 + k];
            if (vv == 0 || vv == 256) val.y = 0.0f;
            b0[k * 512 + vv] = val;
        }
    }
    __syncthreads();
    // Hermitian extension: v in [257,512): b0[v] = conj(b0[512-v]); 1020 entries
#pragma unroll
    for (int i = 0; i < 4; ++i) {
        int e = tid + 256 * i;
        if (e < 1020) {
            int k = e & 3, vv = 257 + (e >> 2);
            float2 s = b0[k * 512 + (512 - vv)];
            b0[k * 512 + vv] = make_float2(s.x, -s.y);
        }
    }
    __syncthreads();
    float2* res = fft512<4>(b0, b1, tbl, tid, true);
    const float sc = 1.0f / 512.0f;
#pragma unroll
    for (int k = 0; k < 4; ++k) {
        float* dst = out + ((size_t)no * 512 + h0 + k) * 512;
        dst[tid]       = res[k * 512 + tid].x * sc;
        dst[tid + 256] = res[k * 512 + tid + 256].x * sc;
    }
}

extern "C" void kernel_launch(void* const* d_in, const int* in_sizes, int n_in,
                              void* d_out, int out_size, void* d_ws, size_t ws_size,
                              hipStream_t stream) {
    const float* x  = (const float*)d_in[0];
    const float* wr = (const float*)d_in[1];
    const float* wi = (const float*)d_in[2];
    const float* br = (const float*)d_in[3];
    const float* bi = (const float*)d_in[4];
    float* out = (float*)d_out;

    const size_t bufElems = (size_t)128 * 257 * 512;  // complex elements
    float2* A = (float2*)d_ws;
    float2* B = A + bufElems;

    k_row_rfft<<<128 * 512, 256, 0, stream>>>(x, A);          // x -> G (A)
    k_col_fft<<<128 * 65, 256, 0, stream>>>(A, B);            // G -> XT (B)
    k_conv<<<8 * 257 * 8, 256, 0, stream>>>(B, A, wr, wi, br, bi);  // XT -> YT (A)
    k_col_ifft<<<128 * 65, 256, 0, stream>>>(A, B);           // YT -> ZT (B)
    k_row_irfft<<<128 * 128, 256, 0, stream>>>(B, out);       // ZT -> out
}

// Round 3
// 884.493 us; speedup vs baseline: 1.1822x; 1.1822x over previous
//
#include <hip/hip_runtime.h>
#include <math.h>

#define PI_F 3.14159265358979323846f

__device__ inline float2 cmulf(float2 a, float2 b) {
    return make_float2(a.x * b.x - a.y * b.y, a.x * b.y + a.y * b.x);
}

// Complex MAC: a += w * v
__device__ inline void cmac(float2& a, float2 w, float2 v) {
    a.x = fmaf(w.x, v.x, a.x);
    a.x = fmaf(-w.y, v.y, a.x);
    a.y = fmaf(w.x, v.y, a.y);
    a.y = fmaf(w.y, v.x, a.y);
}

// 512-point Stockham radix-2 FFT over NCOLS interleaved transforms.
// Data in a[col*512 + i]; b is ping-pong workspace. 256 threads.
// tbl[k] = exp(-2*pi*i*k/512), k in [0,256). inv: conjugate twiddles (no 1/N).
template <int NCOLS>
__device__ inline float2* fft512(float2* a, float2* b, const float2* tbl, int tid, bool inv) {
    for (int st = 0; st < 9; ++st) {
        int p = tid >> st;
        float2 w = tbl[p << st];
        if (inv) w.y = -w.y;
        int i0 = tid;
        int i1 = tid + 256;
        int o0 = tid + ((tid >> st) << st);
        int o1 = o0 + (1 << st);
#pragma unroll
        for (int k = 0; k < NCOLS; ++k) {
            float2 A = a[k * 512 + i0];
            float2 B = a[k * 512 + i1];
            float2 s = make_float2(A.x + B.x, A.y + B.y);
            float2 d = make_float2(A.x - B.x, A.y - B.y);
            b[k * 512 + o0] = s;
            b[k * 512 + o1] = cmulf(d, w);
        }
        __syncthreads();
        float2* t = a; a = b; b = t;
    }
    return a;
}

__device__ inline void build_tbl(float2* tbl, int tid) {
    float ang = -2.0f * PI_F * (float)tid * (1.0f / 512.0f);
    tbl[tid] = make_float2(cosf(ang), sinf(ang));
}

// K1: real FFT of each row of x.
__global__ __launch_bounds__(256) void k_row_rfft(const float* __restrict__ x,
                                                  float2* __restrict__ G) {
    __shared__ float2 b0[512], b1[512], tbl[256];
    int tid = threadIdx.x;
    int row = blockIdx.x;  // nc*512 + h
    build_tbl(tbl, tid);
    const float* xr = x + (size_t)row * 512;
    b0[tid]       = make_float2(xr[tid], 0.0f);
    b0[tid + 256] = make_float2(xr[tid + 256], 0.0f);
    __syncthreads();
    float2* res = fft512<1>(b0, b1, tbl, tid, false);
    float2* g = G + (size_t)row * 257;
    g[tid] = res[tid];
    if (tid == 0) g[256] = res[256];
}

// K2: FFT along h for 4 adjacent columns v0..v0+3.
__global__ __launch_bounds__(256) void k_col_fft(const float2* __restrict__ G,
                                                 float2* __restrict__ XT) {
    __shared__ float2 b0[2048], b1[2048], tbl[256];
    int tid = threadIdx.x;
    int nc = blockIdx.x / 65;
    int v0 = (blockIdx.x % 65) * 4;
    build_tbl(tbl, tid);
#pragma unroll
    for (int i = 0; i < 8; ++i) {
        int e = tid + 256 * i;
        int k = e & 3, h = e >> 2;
        int v = v0 + k;
        float2 val = make_float2(0.0f, 0.0f);
        if (v < 257) val = G[((size_t)nc * 512 + h) * 257 + v];
        b0[k * 512 + h] = val;
    }
    __syncthreads();
    float2* res = fft512<4>(b0, b1, tbl, tid, false);
#pragma unroll
    for (int k = 0; k < 4; ++k) {
        int v = v0 + k;
        if (v < 257) {
            float2* dst = XT + ((size_t)nc * 257 + v) * 512;
            dst[tid]       = res[k * 512 + tid];
            dst[tid + 256] = res[k * 512 + tid + 256];
        }
    }
}

// K3: complex 3x3 conv, 16->16 channels, zero padding, on the half-spectrum.
// Y[o,u,v] = b[o] + sum_{c,kh,kw} w[c,o,kh,kw] * X[c, u-(kh-1), v-(kw-1)]
// Thread = (o, ul); each thread computes 4 CONTIGUOUS u = u0 + 4*ul + j.
// X tile staged with +2-per-4 pad: idx' = uu + 2*(uu>>2), row stride 98 complex
// -> b128 lane addresses land 2-way per bank group (free), 16B aligned.
__global__ __launch_bounds__(256) void k_conv(const float2* __restrict__ XT,
                                              float2* __restrict__ YT,
                                              const float* __restrict__ wr,
                                              const float* __restrict__ wi,
                                              const float* __restrict__ br,
                                              const float* __restrict__ bi) {
    __shared__ float2 Xs[16 * 3 * 98];  // [c][dv][98-padded uu]
    __shared__ float2 Ws[16 * 9 * 16];  // [c][tap][o]
    int tid = threadIdx.x;
    int bid = blockIdx.x;
    int ut = bid & 7;
    int rest = bid >> 3;
    int v = rest % 257;
    int n = rest / 257;
    int u0 = ut * 64;
#pragma unroll
    for (int kk = 0; kk < 9; ++kk) {
        int l = tid + 256 * kk;  // [0,2304)
        int c = l / 144, o = (l / 9) % 16, t = l % 9;
        Ws[(c * 9 + t) * 16 + o] = make_float2(wr[l], wi[l]);
    }
    // X tile with halo (66 uu per (c,dv) row), zero-padded, padded store index
    for (int l = tid; l < 3168; l += 256) {
        int c = l / 198;
        int rem = l - c * 198;
        int dv = rem / 66;
        int uu = rem - dv * 66;
        int vg = v - 1 + dv;
        int ug = u0 - 1 + uu;
        float2 val = make_float2(0.0f, 0.0f);
        if (vg >= 0 && vg < 257 && ug >= 0 && ug < 512)
            val = XT[(((size_t)n * 16 + c) * 257 + vg) * 512 + ug];
        Xs[(c * 3 + dv) * 98 + uu + 2 * (uu >> 2)] = val;
    }
    __syncthreads();
    int o = tid >> 4, ul = tid & 15;
    float2 acc0, acc1, acc2, acc3;
    {
        float brv = br[o], biv = bi[o];
        acc0 = acc1 = acc2 = acc3 = make_float2(brv, biv);
    }
    for (int c = 0; c < 16; ++c) {
#pragma unroll
        for (int kw = 0; kw < 3; ++kw) {
            // dv row = 2-kw; thread's X window uu = 4*ul .. 4*ul+5
            const float4* xr4 = (const float4*)&Xs[(c * 3 + (2 - kw)) * 98] + 3 * ul;
            float4 xa = xr4[0];  // uu 4ul+0,1
            float4 xb = xr4[1];  // uu 4ul+2,3
            float4 xc = xr4[3];  // uu 4ul+4,5 (skip pad hole)
            float2 X0 = make_float2(xa.x, xa.y);
            float2 X1 = make_float2(xa.z, xa.w);
            float2 X2 = make_float2(xb.x, xb.y);
            float2 X3 = make_float2(xb.z, xb.w);
            float2 X4 = make_float2(xc.x, xc.y);
            float2 X5 = make_float2(xc.z, xc.w);
#pragma unroll
            for (int kh = 0; kh < 3; ++kh) {
                float2 w = Ws[(c * 9 + kh * 3 + kw) * 16 + o];
                // X index offset s = 2-kh
                if (kh == 2) {
                    cmac(acc0, w, X0); cmac(acc1, w, X1);
                    cmac(acc2, w, X2); cmac(acc3, w, X3);
                } else if (kh == 1) {
                    cmac(acc0, w, X1); cmac(acc1, w, X2);
                    cmac(acc2, w, X3); cmac(acc3, w, X4);
                } else {
                    cmac(acc0, w, X2); cmac(acc1, w, X3);
                    cmac(acc2, w, X4); cmac(acc3, w, X5);
                }
            }
        }
    }
    float2* yp = YT + (((size_t)n * 16 + o) * 257 + v) * 512 + u0 + 4 * ul;
    float4* yp4 = (float4*)yp;
    yp4[0] = make_float4(acc0.x, acc0.y, acc1.x, acc1.y);
    yp4[1] = make_float4(acc2.x, acc2.y, acc3.x, acc3.y);
}

// K4: inverse FFT along u (scale 1/512) for 4 columns.
__global__ __launch_bounds__(256) void k_col_ifft(const float2* __restrict__ YT,
                                                  float2* __restrict__ ZT) {
    __shared__ float2 b0[2048], b1[2048], tbl[256];
    int tid = threadIdx.x;
    int no = blockIdx.x / 65;
    int v0 = (blockIdx.x % 65) * 4;
    build_tbl(tbl, tid);
#pragma unroll
    for (int k = 0; k < 4; ++k) {
        int v = v0 + k;
        const float2* src = YT + ((size_t)no * 257 + (v < 257 ? v : 256)) * 512;
        b0[k * 512 + tid]       = src[tid];
        b0[k * 512 + tid + 256] = src[tid + 256];
    }
    __syncthreads();
    float2* res = fft512<4>(b0, b1, tbl, tid, true);
    const float sc = 1.0f / 512.0f;
#pragma unroll
    for (int k = 0; k < 4; ++k) {
        int v = v0 + k;
        if (v < 257) {
            float2* dst = ZT + ((size_t)no * 257 + v) * 512;
            float2 r0 = res[k * 512 + tid];
            float2 r1 = res[k * 512 + tid + 256];
            dst[tid]       = make_float2(r0.x * sc, r0.y * sc);
            dst[tid + 256] = make_float2(r1.x * sc, r1.y * sc);
        }
    }
}

// K5: irfft along v for 4 rows h0..h0+3 (pocketfft c2r: imag of DC/Nyquist ignored).
__global__ __launch_bounds__(256) void k_row_irfft(const float2* __restrict__ ZT,
                                                   float* __restrict__ out) {
    __shared__ float2 b0[2048], b1[2048], tbl[256];
    int tid = threadIdx.x;
    int no = blockIdx.x / 128;
    int h0 = (blockIdx.x % 128) * 4;
    build_tbl(tbl, tid);
#pragma unroll
    for (int i = 0; i < 5; ++i) {
        int e = tid + 256 * i;
        if (e < 1028) {
            int k = e & 3, vv = e >> 2;
            float2 val = ZT[((size_t)no * 257 + vv) * 512 + h0 + k];
            if (vv == 0 || vv == 256) val.y = 0.0f;
            b0[k * 512 + vv] = val;
        }
    }
    __syncthreads();
#pragma unroll
    for (int i = 0; i < 4; ++i) {
        int e = tid + 256 * i;
        if (e < 1020) {
            int k = e & 3, vv = 257 + (e >> 2);
            float2 s = b0[k * 512 + (512 - vv)];
            b0[k * 512 + vv] = make_float2(s.x, -s.y);
        }
    }
    __syncthreads();
    float2* res = fft512<4>(b0, b1, tbl, tid, true);
    const float sc = 1.0f / 512.0f;
#pragma unroll
    for (int k = 0; k < 4; ++k) {
        float* dst = out + ((size_t)no * 512 + h0 + k) * 512;
        dst[tid]       = res[k * 512 + tid].x * sc;
        dst[tid + 256] = res[k * 512 + tid + 256].x * sc;
    }
}

extern "C" void kernel_launch(void* const* d_in, const int* in_sizes, int n_in,
                              void* d_out, int out_size, void* d_ws, size_t ws_size,
                              hipStream_t stream) {
    const float* x  = (const float*)d_in[0];
    const float* wr = (const float*)d_in[1];
    const float* wi = (const float*)d_in[2];
    const float* br = (const float*)d_in[3];
    const float* bi = (const float*)d_in[4];
    float* out = (float*)d_out;

    const size_t bufElems = (size_t)128 * 257 * 512;  // complex elements
    float2* A = (float2*)d_ws;
    float2* B = A + bufElems;

    k_row_rfft<<<128 * 512, 256, 0, stream>>>(x, A);                 // x -> G (A)
    k_col_fft<<<128 * 65, 256, 0, stream>>>(A, B);                   // G -> XT (B)
    k_conv<<<8 * 257 * 8, 256, 0, stream>>>(B, A, wr, wi, br, bi);   // XT -> YT (A)
    k_col_ifft<<<128 * 65, 256, 0, stream>>>(A, B);                  // YT -> ZT (B)
    k_row_irfft<<<128 * 128, 256, 0, stream>>>(B, out);              // ZT -> out
}